// Round 10
// baseline (242.129 us; speedup 1.0000x reference)
//
#include <hip/hip_runtime.h>

#define BB 32
#define NN 256
#define EE 300
#define HH 256
#define KK 8
#define MARGINF 0.2f
#define EP 320   // E padded for K-loop

typedef __attribute__((ext_vector_type(8))) short bf16x8;
typedef __attribute__((ext_vector_type(4))) float f32x4;
typedef __attribute__((ext_vector_type(16))) float f32x16;

__device__ inline ushort f2bf(float f) {
  unsigned u = __float_as_uint(f);
  u += 0x7fffu + ((u >> 16) & 1u);          // RNE
  return (ushort)(u >> 16);
}
__device__ inline float bf2f(ushort s) { return __uint_as_float(((unsigned)s) << 16); }
__device__ inline unsigned cvtpk(float lo, float hi) {   // [lo | hi], RNE via HW
  unsigned r;
  asm("v_cvt_pk_bf16_f32 %0, %1, %2" : "=v"(r) : "v"(lo), "v"(hi));
  return r;
}
__device__ inline void gload_lds16(const ushort* g, ushort* l) {
  __builtin_amdgcn_global_load_lds(
      (const __attribute__((address_space(1))) void*)g,
      (__attribute__((address_space(3))) void*)l, 16, 0, 0);
}

// ---------------------------------------------------------------------------
// wconv: W_a2h/W_c2h fp32 [256][300] -> Wt bf16 fragment tiles, zero-padded.
// 4 elems/thread. Also zeroes the attn completion counter each launch.
// ---------------------------------------------------------------------------
__global__ __launch_bounds__(256) void wconv_kernel(
    const float* __restrict__ Wa, const float* __restrict__ Wc,
    ushort* __restrict__ Wt, unsigned* __restrict__ counter)
{
  const int i = blockIdx.x * 256 + threadIdx.x;   // 40960 threads
  if (i == 0) counter[0] = 0u;
  const int base = i * 4;                         // elem id in 163840
  const int w = base / 81920;
  int r = base - w * 81920;
  const int hb = r / 5120; r -= hb * 5120;
  const int ks = r / 512;  r -= ks * 512;
  const int l = r >> 3, jq = r & 7;               // jq in {0,4}
  const int h = hb * 16 + (l & 15);
  const int e0 = ks * 32 + (l >> 4) * 8 + jq;     // %4 == 0
  const float* src = w ? Wc : Wa;
  ushort4 o = {0, 0, 0, 0};
  if (e0 < EE) {                                  // all 4 valid (300%4==0)
    const float4 v = *(const float4*)&src[h * EE + e0];
    o.x = f2bf(v.x); o.y = f2bf(v.y); o.z = f2bf(v.z); o.w = f2bf(v.w);
  }
  *(ushort4*)&Wt[base] = o;
}

// ---------------------------------------------------------------------------
// proj: one WG per (which,b,32-row n-tile), full H=256 output.  (r7-exact)
// ---------------------------------------------------------------------------
__global__ __launch_bounds__(256, 3) void proj_kernel(
    const float* __restrict__ he_a, const float* __restrict__ he_p,
    const float* __restrict__ he_n, const ushort* __restrict__ Wt,
    const float* __restrict__ b_a2h, const float* __restrict__ b_c2h,
    ushort* __restrict__ AT)
{
  const int z = blockIdx.y;           // 96 = 3*BB
  const int which = z >> 5;
  const int b = z & 31;
  const int nb = blockIdx.x;          // 0..7
  const int n0 = nb * 32;
  const int tid = threadIdx.x;
  const int wv = tid >> 6;
  const int lane = tid & 63;
  const int col = lane & 15;
  const int quad = lane >> 4;

  const float* X = (which == 0 ? he_a : which == 1 ? he_p : he_n) + (size_t)b * NN * EE;
  const ushort* W = Wt + (size_t)(which == 0 ? 0 : 1) * 81920;
  const float* bias = (which == 0 ? b_a2h : b_c2h);

  __shared__ __align__(16) ushort sX[32][328];
  __shared__ __align__(16) ushort tr[32][264];

  // ---- stage X tile: 32 rows x 320 bf16 (zero-pad past 300); 8 thr/row
  {
    const int row = tid >> 3, seg = tid & 7;
    const float* xr = X + (size_t)(n0 + row) * EE;
#pragma unroll
    for (int q = 0; q < 10; q++) {
      const int jj = seg + 8 * q;          // float4 slot 0..79 (75 valid)
      float4 xv = {0.f, 0.f, 0.f, 0.f};
      if (jj < 75) xv = *(const float4*)&xr[4 * jj];
      uint2 p; p.x = cvtpk(xv.x, xv.y); p.y = cvtpk(xv.z, xv.w);
      *(uint2*)&sX[row][4 * jj] = p;
    }
  }
  __syncthreads();

  f32x4 acc[2][4];
#pragma unroll
  for (int nf = 0; nf < 2; nf++)
#pragma unroll
    for (int mb = 0; mb < 4; mb++) acc[nf][mb] = (f32x4){0.f, 0.f, 0.f, 0.f};

#pragma unroll
  for (int ks = 0; ks < 10; ks++) {
    const int off = 32 * ks + 8 * quad;
    const bf16x8 a0 = *(const bf16x8*)&sX[col][off];
    const bf16x8 a1 = *(const bf16x8*)&sX[16 + col][off];
#pragma unroll
    for (int mb = 0; mb < 4; mb++) {
      const bf16x8 w8 = *(const bf16x8*)&W[(4 * wv + mb) * 5120 + ks * 512 + lane * 8];
      acc[0][mb] = __builtin_amdgcn_mfma_f32_16x16x32_bf16(a0, w8, acc[0][mb], 0, 0, 0);
      acc[1][mb] = __builtin_amdgcn_mfma_f32_16x16x32_bf16(a1, w8, acc[1][mb], 0, 0, 0);
    }
  }

  // ---- epilogue: +bias, bf16, transpose through LDS, coalesced tiled store
#pragma unroll
  for (int nf = 0; nf < 2; nf++)
#pragma unroll
    for (int mb = 0; mb < 4; mb++) {
      const float bi = bias[64 * wv + 16 * mb + col];
#pragma unroll
      for (int r = 0; r < 4; r++)
        tr[16 * nf + 4 * quad + r][64 * wv + 16 * mb + col] = f2bf(acc[nf][mb][r] + bi);
    }
  __syncthreads();
  {
    ushort* dst = AT + (size_t)(which * BB + b) * (NN * HH) + (size_t)nb * 8192;
#pragma unroll
    for (int it = 0; it < 4; it++) {
      const int c = it * 256 + tid;            // chunk id: hb*64 + hs*32 + row
      const int row = c & 31, hs = (c >> 5) & 1, hb = c >> 6;
      *(uint4*)&dst[c * 8] = *(const uint4*)&tr[row][hb * 16 + hs * 8];
    }
  }
}

// ---------------------------------------------------------------------------
// attn v10: 512-thread 1-block/CU free-run (occupancy LDS-pinned -> VGPR
// free up to 512/wave). BOTH n-block fragment sets resident (saf/gaf x2,
// 256 VGPR) so each B-fragment ds_read feeds 4 MFMAs (1:4, was 1:2) -> LDS
// reads per wave halve (256->128). 8 single-m-block bodies of 64 MFMA,
// ping-ponged across two statically-named acc sets with the previous body's
// exp-tail woven 2 elems/ks (bounded weave; body pairs in an unroll-1 loop).
// ---------------------------------------------------------------------------
__global__ __launch_bounds__(512, 1) void attn_kernel(
    const ushort* __restrict__ AT, const float* __restrict__ Watt,
    const float* __restrict__ Wfc, const float* __restrict__ bfc,
    float* __restrict__ scoresK, unsigned* __restrict__ counter,
    float* __restrict__ out)
{
  const int d = blockIdx.x;             // 256 blocks
  const int x = d & 7;
  const int j = d >> 3;                 // 0..31
  const int grp = x * 8 + (j & 7);      // (which,b) group 0..63
  const int kp = j >> 3;                // k-pair 0..3
  const int which = grp >> 5;
  const int b = grp & 31;
  const int tid = threadIdx.x;
  const int wid = tid >> 6;             // 0..7
  const int kh = wid >> 2;              // head half: 0 or 1
  const int ws = wid & 3;               // sub-wave within head
  const int lane = tid & 63;

  const ushort* Ta = AT + (size_t)b * (NN * HH);                       // anchor tiles
  const ushort* Tc = AT + (size_t)((1 + which) * BB + b) * (NN * HH);  // pos/neg tiles

  __shared__ __align__(16) ushort sB[65536];      // FULL Tc tile, 128 KB
  __shared__ __align__(16) ushort wkb[2][256];    // Watt rows * log2e (bf16)
  __shared__ __align__(16) ushort wfb[2][256];    // Wfc rows (bf16)
  __shared__ float red[16];
  __shared__ unsigned isLast;

  // ---- issue async stage of the full 128KB Tc (16 x 1KB per wave)
#pragma unroll
  for (int it = 0; it < 16; it++) {
    const int off = (wid * 16 + it) * 512;        // ushort index, wave-uniform
    gload_lds16(Tc + off + lane * 8, &sB[off]);
  }
  // ---- weights -> bf16 LDS (completes alongside the stage)
  {
    const int h = tid & 255, hd = tid >> 8;
    const int kt = 2 * kp + hd;
    wkb[hd][h] = f2bf(Watt[(size_t)kt * HH + h] * 1.44269504089f);  // fold log2e
    wfb[hd][h] = f2bf(Wfc[(size_t)kt * HH + h]);
  }
  __syncthreads();   // stage + weights complete; ONLY barrier before reduce

  const ushort* wkp = wkb[kh];
  const ushort* wfp = wfb[kh];

  float num = 0.f, den = 0.f;

  // ---- pack BOTH n-block A-fragment sets (w- and f-scaled): nbk = ws, 4+ws
  bf16x8 saf0[16], gaf0[16], saf1[16], gaf1[16];
#define PACK(SAF, GAF, NBK)                                                    \
  {                                                                            \
    const ushort* abase = Ta + (NBK) * 8192 + lane * 8;                        \
    _Pragma("unroll")                                                          \
    for (int ks = 0; ks < 16; ks++) {                                          \
      const bf16x8 a = *(const bf16x8*)&abase[ks * 512];                       \
      const int off = 16 * ks + 8 * (lane >> 5);                               \
      const bf16x8 w8 = *(const bf16x8*)&wkp[off];                             \
      const bf16x8 f8 = *(const bf16x8*)&wfp[off];                             \
      union { bf16x8 v; unsigned u[4]; } sv, gv;                               \
      _Pragma("unroll")                                                        \
      for (int jj = 0; jj < 4; jj++) {                                         \
        const float a0 = bf2f((ushort)a[2 * jj]), a1 = bf2f((ushort)a[2 * jj + 1]); \
        sv.u[jj] = cvtpk(a0 * bf2f((ushort)w8[2 * jj]), a1 * bf2f((ushort)w8[2 * jj + 1])); \
        gv.u[jj] = cvtpk(a0 * bf2f((ushort)f8[2 * jj]), a1 * bf2f((ushort)f8[2 * jj + 1])); \
      }                                                                        \
      SAF[ks] = sv.v; GAF[ks] = gv.v;                                          \
    }                                                                          \
  }
  PACK(saf0, gaf0, ws)
  PACK(saf1, gaf1, 4 + ws)
#undef PACK

  // ---- 8 m-block bodies; each: 16 ds_reads feed 64 MFMAs (1:4)
  const int rot = wid;                            // per-wave m-order stagger
  f32x16 aSA0, aGA0, aSA1, aGA1, aSB0, aGB0, aSB1, aGB1;

#define BODY(AS0, AG0, AS1, AG1, MBASE, PS0, PG0, PS1, PG1, DOW)               \
    AS0 = (f32x16){0,0,0,0,0,0,0,0,0,0,0,0,0,0,0,0};                          \
    AG0 = (f32x16){0,0,0,0,0,0,0,0,0,0,0,0,0,0,0,0};                          \
    AS1 = (f32x16){0,0,0,0,0,0,0,0,0,0,0,0,0,0,0,0};                          \
    AG1 = (f32x16){0,0,0,0,0,0,0,0,0,0,0,0,0,0,0,0};                          \
    __builtin_amdgcn_s_setprio(1);                                             \
    _Pragma("unroll")                                                          \
    for (int ks = 0; ks < 16; ks++) {                                          \
      const bf16x8 bv = *(const bf16x8*)&sB[(MBASE) + ks * 512 + lane * 8];    \
      AS0 = __builtin_amdgcn_mfma_f32_32x32x16_bf16(saf0[ks], bv, AS0, 0, 0, 0);\
      AG0 = __builtin_amdgcn_mfma_f32_32x32x16_bf16(gaf0[ks], bv, AG0, 0, 0, 0);\
      AS1 = __builtin_amdgcn_mfma_f32_32x32x16_bf16(saf1[ks], bv, AS1, 0, 0, 0);\
      AG1 = __builtin_amdgcn_mfma_f32_32x32x16_bf16(gaf1[ks], bv, AG1, 0, 0, 0);\
      if (DOW) {                                                               \
        const float p0 = exp2f(PS0[ks]); den += p0; num = fmaf(p0, PG0[ks], num); \
        const float p1 = exp2f(PS1[ks]); den += p1; num = fmaf(p1, PG1[ks], num); \
      }                                                                        \
    }                                                                          \
    __builtin_amdgcn_s_setprio(0);

  BODY(aSA0, aGA0, aSA1, aGA1, ((0 + rot) & 7) * 8192,
       aSB0, aGB0, aSB1, aGB1, 0)
#pragma unroll 1
  for (int mi = 0; mi < 3; mi++) {
    const int m1 = ((2 * mi + 1 + rot) & 7) * 8192;
    const int m2 = ((2 * mi + 2 + rot) & 7) * 8192;
    BODY(aSB0, aGB0, aSB1, aGB1, m1, aSA0, aGA0, aSA1, aGA1, 1)
    BODY(aSA0, aGA0, aSA1, aGA1, m2, aSB0, aGB0, aSB1, aGB1, 1)
  }
  {
    const int m7 = ((7 + rot) & 7) * 8192;
    BODY(aSB0, aGB0, aSB1, aGB1, m7, aSA0, aGA0, aSA1, aGA1, 1)
  }
#undef BODY
  // final tail of the last body (set B)
#pragma unroll
  for (int r = 0; r < 16; r++) {
    const float p0 = exp2f(aSB0[r]);
    den += p0; num = fmaf(p0, aGB0[r], num);
    const float p1 = exp2f(aSB1[r]);
    den += p1; num = fmaf(p1, aGB1[r], num);
  }

  // ---- per-head reduce (waves 0-3 -> head 2kp, waves 4-7 -> head 2kp+1)
#pragma unroll
  for (int off = 32; off >= 1; off >>= 1) {
    num += __shfl_xor(num, off);
    den += __shfl_xor(den, off);
  }
  if (lane == 0) { red[wid] = num; red[8 + wid] = den; }
  __syncthreads();
  if (tid == 0) {
    const float n0 = red[0] + red[1] + red[2] + red[3];
    const float d0 = red[8] + red[9] + red[10] + red[11];
    const float n1 = red[4] + red[5] + red[6] + red[7];
    const float d1 = red[12] + red[13] + red[14] + red[15];
    atomicExch(&scoresK[(2 * kp) * 64 + grp], n0 / d0);
    atomicExch(&scoresK[(2 * kp + 1) * 64 + grp], n1 / d1);
    __threadfence();
    isLast = (atomicAdd(counter, 1u) == 255u) ? 1u : 0u;
  }
  __syncthreads();

  // ---- fused loss: last block's wave 0 reduces all 512 scores
  if (isLast && tid < 64) {
    float s = bfc[0];                        // tid = which*32 + b
#pragma unroll
    for (int kk = 0; kk < KK; kk++)
      s += atomicAdd(&scoresK[kk * 64 + tid], 0.0f);   // coherent read
    const float other = __shfl(s, tid + 32);
    float v = 0.f;
    if (tid < 32) v = fmaxf(other - s + MARGINF, 0.f);
#pragma unroll
    for (int off = 32; off >= 1; off >>= 1) v += __shfl_xor(v, off);
    if (tid == 0) out[0] = v * (1.0f / 32.0f);
  }
}

// ---------------------------------------------------------------------------
extern "C" void kernel_launch(void* const* d_in, const int* in_sizes, int n_in,
                              void* d_out, int out_size, void* d_ws, size_t ws_size,
                              hipStream_t stream) {
  const float* he_a  = (const float*)d_in[0];
  const float* he_p  = (const float*)d_in[1];
  const float* he_n  = (const float*)d_in[2];
  const float* W_a2h = (const float*)d_in[3];
  const float* b_a2h = (const float*)d_in[4];
  const float* W_c2h = (const float*)d_in[5];
  const float* b_c2h = (const float*)d_in[6];
  const float* W_att = (const float*)d_in[7];
  // d_in[8] = b_att: cancels in global softmax
  const float* W_fc  = (const float*)d_in[9];
  const float* b_fc  = (const float*)d_in[10];

  ushort* AT = (ushort*)d_ws;                                // [3][B][8][16][64][8] bf16, 12.6 MB
  float* scoresK = (float*)(AT + (size_t)3 * BB * NN * HH);  // [512] fp32
  ushort* Wt = (ushort*)(scoresK + 512);                     // [2][16][10][64][8] bf16, 320 KB
  unsigned* counter = (unsigned*)(Wt + (size_t)2 * HH * EP); // [1]
  (void)ws_size; (void)in_sizes; (void)n_in; (void)out_size;

  wconv_kernel<<<160, 256, 0, stream>>>(W_a2h, W_c2h, Wt, counter);
  dim3 pg(8, 96);
  proj_kernel<<<pg, 256, 0, stream>>>(he_a, he_p, he_n, Wt, b_a2h, b_c2h, AT);
  attn_kernel<<<256, 512, 0, stream>>>(AT, W_att, W_fc, b_fc, scoresK, counter, (float*)d_out);
}

// Round 12
// 131.954 us; speedup vs baseline: 1.8349x; 1.8349x over previous
//
#include <hip/hip_runtime.h>

#define BB 32
#define NN 256
#define EE 300
#define HH 256
#define KK 8
#define MARGINF 0.2f
#define EP 320   // E padded for K-loop

typedef __attribute__((ext_vector_type(8))) short bf16x8;
typedef __attribute__((ext_vector_type(4))) float f32x4;
typedef __attribute__((ext_vector_type(16))) float f32x16;

__device__ inline ushort f2bf(float f) {
  unsigned u = __float_as_uint(f);
  u += 0x7fffu + ((u >> 16) & 1u);          // RNE
  return (ushort)(u >> 16);
}
__device__ inline float bf2f(ushort s) { return __uint_as_float(((unsigned)s) << 16); }
__device__ inline unsigned cvtpk(float lo, float hi) {   // [lo | hi], RNE via HW
  unsigned r;
  asm("v_cvt_pk_bf16_f32 %0, %1, %2" : "=v"(r) : "v"(lo), "v"(hi));
  return r;
}
__device__ inline void gload_lds16(const ushort* g, ushort* l) {
  __builtin_amdgcn_global_load_lds(
      (const __attribute__((address_space(1))) void*)g,
      (__attribute__((address_space(3))) void*)l, 16, 0, 0);
}

// ---------------------------------------------------------------------------
// wconv: W_a2h/W_c2h fp32 [256][300] -> Wt bf16 fragment tiles, zero-padded.
// Tile layout: [w(2)][hb(16)][ks(10)][lane(64)][8], lane l: h=hb*16+(l&15),
// e=ks*32+(l>>4)*8+j. Also zeroes the attn completion counter each launch.
// ---------------------------------------------------------------------------
__global__ __launch_bounds__(256) void wconv_kernel(
    const float* __restrict__ Wa, const float* __restrict__ Wc,
    ushort* __restrict__ Wt, unsigned* __restrict__ counter)
{
  const int i = blockIdx.x * 256 + threadIdx.x;   // over 2*16*10*512 = 163840
  if (i == 0) counter[0] = 0u;
  const int w = i / 81920;
  int r = i - w * 81920;
  const int hb = r / 5120; r -= hb * 5120;
  const int ks = r / 512;  r -= ks * 512;
  const int l = r >> 3, j = r & 7;
  const int h = hb * 16 + (l & 15);
  const int e = ks * 32 + (l >> 4) * 8 + j;
  const float* src = w ? Wc : Wa;
  Wt[i] = (e < EE) ? f2bf(src[h * EE + e]) : (ushort)0;
}

// ---------------------------------------------------------------------------
// proj: one WG per (which,b,32-row n-tile), full H=256 output.
// X tile staged to LDS; W fragments read as coalesced 1KB tile loads.
// Output written in fragment-tile layout so attn's operand loads are linear.
// ---------------------------------------------------------------------------
__global__ __launch_bounds__(256, 3) void proj_kernel(
    const float* __restrict__ he_a, const float* __restrict__ he_p,
    const float* __restrict__ he_n, const ushort* __restrict__ Wt,
    const float* __restrict__ b_a2h, const float* __restrict__ b_c2h,
    ushort* __restrict__ AT)
{
  const int z = blockIdx.y;           // 96 = 3*BB
  const int which = z >> 5;
  const int b = z & 31;
  const int nb = blockIdx.x;          // 0..7
  const int n0 = nb * 32;
  const int tid = threadIdx.x;
  const int wv = tid >> 6;
  const int lane = tid & 63;
  const int col = lane & 15;
  const int quad = lane >> 4;

  const float* X = (which == 0 ? he_a : which == 1 ? he_p : he_n) + (size_t)b * NN * EE;
  const ushort* W = Wt + (size_t)(which == 0 ? 0 : 1) * 81920;
  const float* bias = (which == 0 ? b_a2h : b_c2h);

  __shared__ __align__(16) ushort sX[32][328];
  __shared__ __align__(16) ushort tr[32][264];

  // ---- stage X tile: 32 rows x 320 bf16 (zero-pad past 300); 8 thr/row
  {
    const int row = tid >> 3, seg = tid & 7;
    const float* xr = X + (size_t)(n0 + row) * EE;
#pragma unroll
    for (int q = 0; q < 10; q++) {
      const int jj = seg + 8 * q;          // float4 slot 0..79 (75 valid)
      float4 xv = {0.f, 0.f, 0.f, 0.f};
      if (jj < 75) xv = *(const float4*)&xr[4 * jj];
      uint2 p; p.x = cvtpk(xv.x, xv.y); p.y = cvtpk(xv.z, xv.w);
      *(uint2*)&sX[row][4 * jj] = p;
    }
  }
  __syncthreads();

  f32x4 acc[2][4];
#pragma unroll
  for (int nf = 0; nf < 2; nf++)
#pragma unroll
    for (int mb = 0; mb < 4; mb++) acc[nf][mb] = (f32x4){0.f, 0.f, 0.f, 0.f};

#pragma unroll
  for (int ks = 0; ks < 10; ks++) {
    const int off = 32 * ks + 8 * quad;
    const bf16x8 a0 = *(const bf16x8*)&sX[col][off];
    const bf16x8 a1 = *(const bf16x8*)&sX[16 + col][off];
#pragma unroll
    for (int mb = 0; mb < 4; mb++) {
      const bf16x8 w8 = *(const bf16x8*)&W[(4 * wv + mb) * 5120 + ks * 512 + lane * 8];
      acc[0][mb] = __builtin_amdgcn_mfma_f32_16x16x32_bf16(a0, w8, acc[0][mb], 0, 0, 0);
      acc[1][mb] = __builtin_amdgcn_mfma_f32_16x16x32_bf16(a1, w8, acc[1][mb], 0, 0, 0);
    }
  }

  // ---- epilogue: +bias, bf16, transpose through LDS, coalesced tiled store
#pragma unroll
  for (int nf = 0; nf < 2; nf++)
#pragma unroll
    for (int mb = 0; mb < 4; mb++) {
      const float bi = bias[64 * wv + 16 * mb + col];
#pragma unroll
      for (int r = 0; r < 4; r++)
        tr[16 * nf + 4 * quad + r][64 * wv + 16 * mb + col] = f2bf(acc[nf][mb][r] + bi);
    }
  __syncthreads();
  {
    ushort* dst = AT + (size_t)(which * BB + b) * (NN * HH) + (size_t)nb * 8192;
#pragma unroll
    for (int it = 0; it < 4; it++) {
      const int c = it * 256 + tid;            // chunk id: hb*64 + hs*32 + row
      const int row = c & 31, hs = (c >> 5) & 1, hb = c >> 6;
      *(uint4*)&dst[c * 8] = *(const uint4*)&tr[row][hb * 16 + hs * 8];
    }
  }
}

// ---------------------------------------------------------------------------
// attn v5 (verified 132.5 total): ONE 512-thread block per CU (grid 256),
// block = (which,b,k-pair). Full 128KB Tc staged to LDS ONCE via
// global_load_lds; after ONE barrier the 8 waves free-run with ZERO inner
// barriers. Waves 0-3 compute head 2kp, waves 4-7 head 2kp+1; per wave:
// 2 packed n-sets x 4 m-tile-pairs, 64-MFMA clusters. Weights pre-rounded
// to bf16 in LDS. Wave-staggered (s, mtp) order decorrelates LDS bursts.
// NOTE: 512-thr block => 8 waves resident => hard cap 256 VGPR/wave; the
// live set (~220) fits. Do NOT add resident state (v6/v10 spilled).
// ---------------------------------------------------------------------------
__global__ __launch_bounds__(512, 1) void attn_kernel(
    const ushort* __restrict__ AT, const float* __restrict__ Watt,
    const float* __restrict__ Wfc, const float* __restrict__ bfc,
    float* __restrict__ scoresK, unsigned* __restrict__ counter,
    float* __restrict__ out)
{
  const int d = blockIdx.x;             // 256 blocks
  // HW round-robins d -> XCD d%8; give XCD x the 8 (which,b) groups [8x,8x+8)
  const int x = d & 7;
  const int j = d >> 3;                 // 0..31
  const int grp = x * 8 + (j & 7);      // (which,b) group 0..63
  const int kp = j >> 3;                // k-pair 0..3
  const int which = grp >> 5;
  const int b = grp & 31;
  const int tid = threadIdx.x;
  const int wid = tid >> 6;             // 0..7
  const int kh = wid >> 2;              // head half: 0 or 1
  const int ws = wid & 3;               // sub-wave within head
  const int lane = tid & 63;

  const ushort* Ta = AT + (size_t)b * (NN * HH);                       // anchor tiles
  const ushort* Tc = AT + (size_t)((1 + which) * BB + b) * (NN * HH);  // pos/neg tiles

  __shared__ __align__(16) ushort sB[65536];      // FULL Tc tile, 128 KB
  __shared__ __align__(16) ushort wkb[2][256];    // Watt rows (bf16) for 2 heads
  __shared__ __align__(16) ushort wfb[2][256];    // Wfc rows (bf16)
  __shared__ float red[16];
  __shared__ unsigned isLast;

  // ---- issue async stage of the full 128KB Tc (16 x 1KB per wave)
#pragma unroll
  for (int it = 0; it < 16; it++) {
    const int off = (wid * 16 + it) * 512;        // ushort index, wave-uniform
    gload_lds16(Tc + off + lane * 8, &sB[off]);
  }
  // ---- weights -> bf16 LDS (completes alongside the stage)
  {
    const int h = tid & 255, hd = tid >> 8;
    const int kt = 2 * kp + hd;
    wkb[hd][h] = f2bf(Watt[(size_t)kt * HH + h]);
    wfb[hd][h] = f2bf(Wfc[(size_t)kt * HH + h]);
  }
  __syncthreads();   // stage + weights complete; ONLY barrier before reduce

  const ushort* wkp = wkb[kh];
  const ushort* wfp = wfb[kh];

  float num = 0.f, den = 0.f;

#pragma unroll 1
  for (int si = 0; si < 2; si++) {
    const int s = si ^ kh;                        // stagger s order across heads
    // ---- pack this wave's A-fragments (w- and f-scaled), n-block = 4s+ws
    bf16x8 saf[16], gaf[16];
    {
      const ushort* abase = Ta + (4 * s + ws) * 8192 + lane * 8;
#pragma unroll
      for (int ks = 0; ks < 16; ks++) {
        const bf16x8 a = *(const bf16x8*)&abase[ks * 512];   // coalesced, L2-hot
        const int off = 16 * ks + 8 * (lane >> 5);
        const bf16x8 w8 = *(const bf16x8*)&wkp[off];
        const bf16x8 f8 = *(const bf16x8*)&wfp[off];
        union { bf16x8 v; unsigned u[4]; } sv, gv;
#pragma unroll
        for (int jj = 0; jj < 4; jj++) {
          const float a0 = bf2f((ushort)a[2 * jj]), a1 = bf2f((ushort)a[2 * jj + 1]);
          sv.u[jj] = cvtpk(a0 * bf2f((ushort)w8[2 * jj]), a1 * bf2f((ushort)w8[2 * jj + 1]));
          gv.u[jj] = cvtpk(a0 * bf2f((ushort)f8[2 * jj]), a1 * bf2f((ushort)f8[2 * jj + 1]));
        }
        saf[ks] = sv.v; gaf[ks] = gv.v;
      }
    }

#pragma unroll 1
    for (int mi = 0; mi < 4; mi++) {
      const int mtp = (mi + ws) & 3;              // stagger m-tile order across waves
      const int mbase = mtp * 16384;
      f32x16 aS0 = {0,0,0,0,0,0,0,0,0,0,0,0,0,0,0,0};
      f32x16 aG0 = {0,0,0,0,0,0,0,0,0,0,0,0,0,0,0,0};
      f32x16 aS1 = {0,0,0,0,0,0,0,0,0,0,0,0,0,0,0,0};
      f32x16 aG1 = {0,0,0,0,0,0,0,0,0,0,0,0,0,0,0,0};
      __builtin_amdgcn_s_setprio(1);
#pragma unroll
      for (int ks = 0; ks < 16; ks++) {
        const bf16x8 b0 = *(const bf16x8*)&sB[mbase + ks * 512 + lane * 8];
        const bf16x8 b1 = *(const bf16x8*)&sB[mbase + 8192 + ks * 512 + lane * 8];
        aS0 = __builtin_amdgcn_mfma_f32_32x32x16_bf16(saf[ks], b0, aS0, 0, 0, 0);
        aG0 = __builtin_amdgcn_mfma_f32_32x32x16_bf16(gaf[ks], b0, aG0, 0, 0, 0);
        aS1 = __builtin_amdgcn_mfma_f32_32x32x16_bf16(saf[ks], b1, aS1, 0, 0, 0);
        aG1 = __builtin_amdgcn_mfma_f32_32x32x16_bf16(gaf[ks], b1, aG1, 0, 0, 0);
      }
      __builtin_amdgcn_s_setprio(0);
#pragma unroll
      for (int r = 0; r < 16; r++) {
        const float p0 = __expf(aS0[r]);
        den += p0; num = fmaf(p0, aG0[r], num);
        const float p1 = __expf(aS1[r]);
        den += p1; num = fmaf(p1, aG1[r], num);
      }
    }
  }

  // ---- per-head reduce (waves 0-3 -> head 2kp, waves 4-7 -> head 2kp+1)
#pragma unroll
  for (int off = 32; off >= 1; off >>= 1) {
    num += __shfl_xor(num, off);
    den += __shfl_xor(den, off);
  }
  if (lane == 0) { red[wid] = num; red[8 + wid] = den; }
  __syncthreads();
  if (tid == 0) {
    const float n0 = red[0] + red[1] + red[2] + red[3];
    const float d0 = red[8] + red[9] + red[10] + red[11];
    const float n1 = red[4] + red[5] + red[6] + red[7];
    const float d1 = red[12] + red[13] + red[14] + red[15];
    atomicExch(&scoresK[(2 * kp) * 64 + grp], n0 / d0);
    atomicExch(&scoresK[(2 * kp + 1) * 64 + grp], n1 / d1);
    __threadfence();
    isLast = (atomicAdd(counter, 1u) == 255u) ? 1u : 0u;
  }
  __syncthreads();

  // ---- fused loss: last block's wave 0 reduces all 512 scores
  if (isLast && tid < 64) {
    float s = bfc[0];                        // tid = which*32 + b
#pragma unroll
    for (int kk = 0; kk < KK; kk++)
      s += atomicAdd(&scoresK[kk * 64 + tid], 0.0f);   // coherent read
    const float other = __shfl(s, tid + 32);
    float v = 0.f;
    if (tid < 32) v = fmaxf(other - s + MARGINF, 0.f);
#pragma unroll
    for (int off = 32; off >= 1; off >>= 1) v += __shfl_xor(v, off);
    if (tid == 0) out[0] = v * (1.0f / 32.0f);
  }
}

// ---------------------------------------------------------------------------
extern "C" void kernel_launch(void* const* d_in, const int* in_sizes, int n_in,
                              void* d_out, int out_size, void* d_ws, size_t ws_size,
                              hipStream_t stream) {
  const float* he_a  = (const float*)d_in[0];
  const float* he_p  = (const float*)d_in[1];
  const float* he_n  = (const float*)d_in[2];
  const float* W_a2h = (const float*)d_in[3];
  const float* b_a2h = (const float*)d_in[4];
  const float* W_c2h = (const float*)d_in[5];
  const float* b_c2h = (const float*)d_in[6];
  const float* W_att = (const float*)d_in[7];
  // d_in[8] = b_att: cancels in global softmax
  const float* W_fc  = (const float*)d_in[9];
  const float* b_fc  = (const float*)d_in[10];

  ushort* AT = (ushort*)d_ws;                                // [3][B][8][16][64][8] bf16, 12.6 MB
  float* scoresK = (float*)(AT + (size_t)3 * BB * NN * HH);  // [512] fp32
  ushort* Wt = (ushort*)(scoresK + 512);                     // [2][16][10][64][8] bf16, 320 KB
  unsigned* counter = (unsigned*)(Wt + (size_t)2 * HH * EP); // [1]
  (void)ws_size; (void)in_sizes; (void)n_in; (void)out_size;

  wconv_kernel<<<640, 256, 0, stream>>>(W_a2h, W_c2h, Wt, counter);
  dim3 pg(8, 96);
  proj_kernel<<<pg, 256, 0, stream>>>(he_a, he_p, he_n, Wt, b_a2h, b_c2h, AT);
  attn_kernel<<<256, 512, 0, stream>>>(AT, W_att, W_fc, b_fc, scoresK, counter, (float*)d_out);
}